// Round 7
// baseline (116.203 us; speedup 1.0000x reference)
//
#include <hip/hip_runtime.h>
#include <math.h>

#define NTOK 16384
#define DIM  4096
#define NE   64
#define TOPK 8
#define SPLITK 8
#define NSLICE (DIM / SPLITK / 32)   // 16 k32-slices per wave
#define ROUTE_SCALE 2.5f

typedef __attribute__((ext_vector_type(8))) short short8v;
typedef __attribute__((ext_vector_type(4))) float f32x4;

// exact 3-term bf16 truncation split of 8 f32, packed as 3x short8 (bf16) frags
__device__ __forceinline__ void split3_pack(const float* v, uint4& b0, uint4& b1, uint4& b2)
{
    uint p0[8], p1[8], p2[8];
#pragma unroll
    for (int j = 0; j < 8; ++j) {
        const float xv = v[j];
        const uint  u0 = __float_as_uint(xv) & 0xffff0000u;
        const float f0 = __uint_as_float(u0);
        const float r  = xv - f0;                       // exact
        const uint  u1 = __float_as_uint(r) & 0xffff0000u;
        const float f1 = __uint_as_float(u1);
        const float r2 = r - f1;                        // exact, fits bf16
        const uint  u2 = __float_as_uint(r2) & 0xffff0000u;
        p0[j] = u0; p1[j] = u1; p2[j] = u2;
    }
    b0 = make_uint4(p0[1] | (p0[0] >> 16), p0[3] | (p0[2] >> 16),
                    p0[5] | (p0[4] >> 16), p0[7] | (p0[6] >> 16));
    b1 = make_uint4(p1[1] | (p1[0] >> 16), p1[3] | (p1[2] >> 16),
                    p1[5] | (p1[4] >> 16), p1[7] | (p1[6] >> 16));
    b2 = make_uint4(p2[1] | (p2[0] >> 16), p2[3] | (p2[2] >> 16),
                    p2[5] | (p2[4] >> 16), p2[7] | (p2[6] >> 16));
}

// ---- prep: w -> frag-ready bf16 splits. entry(ks,nt,sp,lane) at (ks*12 + nt*3+sp)*64+lane
__global__ __launch_bounds__(256)
void prep_w(const float* __restrict__ gw, uint4* __restrict__ wS)
{
    const int tid  = blockIdx.x * 256 + threadIdx.x;   // 32768 total
    const int lane = tid & 63;
    const int nt   = (tid >> 6) & 3;
    const int ks   = tid >> 8;                         // 0..127
    const int e    = nt * 16 + (lane & 15);
    const int kb   = ks * 32 + (lane >> 4) * 8;
    float v[8];
    *(float4*)&v[0] = *(const float4*)&gw[(size_t)e * DIM + kb];
    *(float4*)&v[4] = *(const float4*)&gw[(size_t)e * DIM + kb + 4];
    uint4 b0, b1, b2;
    split3_pack(v, b0, b1, b2);
    const size_t base = (size_t)(ks * 4 + nt) * 3 * 64 + lane;
    wS[base] = b0; wS[base + 64] = b1; wS[base + 128] = b2;
}

// ---- fused: 8-wave WG, wave==kh, 64 tokens/WG; gemm -> LDS partials -> top-8 ----
// B single-buffered (L2-resident wS, short lead); x double-buffered (HBM stream).
__global__ __launch_bounds__(512, 2)
void router_fused(const float* __restrict__ x, const uint4* __restrict__ wS,
                  const float* __restrict__ bias, float* __restrict__ out)
{
    __shared__ float part_lds[SPLITK][64][NE];   // 128 KB
    __shared__ int   hist[NE];

    const int t    = threadIdx.x;
    const int lane = t & 63;
    const int wv   = __builtin_amdgcn_readfirstlane(t >> 6);   // wave == kh, 0..7
    const int r    = lane & 15;
    const int g    = lane >> 4;
    const int tok0 = blockIdx.x * 64;
    const int ks0  = wv * NSLICE;              // global k32-slice base

    if (t < NE) hist[t] = 0;

    const float* xr[4];
#pragma unroll
    for (int G = 0; G < 4; ++G)
        xr[G] = x + (size_t)(tok0 + G * 16 + r) * DIM + ks0 * 32 + g * 8;
    const uint4* wB = wS + lane;

    f32x4 acc[16];                              // [nt*4 + G]
#pragma unroll
    for (int i = 0; i < 16; ++i) acc[i] = (f32x4){0.f, 0.f, 0.f, 0.f};

    float xP[32], xQ[32];                       // 4 groups x 8 floats
    uint4 bP[12], bQ[12];                       // live ranges don't overlap (single-buffer)

#define LOADX(X, s) do {                                                     \
        _Pragma("unroll")                                                    \
        for (int G = 0; G < 4; ++G) {                                        \
            *(float4*)&X[G * 8]     = *(const float4*)(xr[G] + (size_t)(s) * 32);     \
            *(float4*)&X[G * 8 + 4] = *(const float4*)(xr[G] + (size_t)(s) * 32 + 4); \
        }                                                                    \
    } while (0)
#define LOADB(B, s) do {                                                     \
        _Pragma("unroll")                                                    \
        for (int i = 0; i < 12; ++i)                                         \
            B[i] = wB[((size_t)(ks0 + (s)) * 12 + i) * 64];                  \
    } while (0)
#define COMPUTE(X, B) do {                                                            \
        _Pragma("unroll")                                                             \
        for (int G = 0; G < 4; ++G) {                                                 \
            uint4 a0u, a1u, a2u;                                                      \
            split3_pack(&X[G * 8], a0u, a1u, a2u);                                    \
            const short8v a0 = *(short8v*)&a0u;                                       \
            const short8v a1 = *(short8v*)&a1u;                                       \
            const short8v a2 = *(short8v*)&a2u;                                       \
            _Pragma("unroll")                                                         \
            for (int nt = 0; nt < 4; ++nt) {                                          \
                const short8v b0 = *(const short8v*)&B[nt * 3 + 0];                   \
                const short8v b1 = *(const short8v*)&B[nt * 3 + 1];                   \
                const short8v b2 = *(const short8v*)&B[nt * 3 + 2];                   \
                f32x4 c = acc[nt * 4 + G];                                            \
                c = __builtin_amdgcn_mfma_f32_16x16x32_bf16(a2, b0, c, 0, 0, 0);      \
                c = __builtin_amdgcn_mfma_f32_16x16x32_bf16(a1, b1, c, 0, 0, 0);      \
                c = __builtin_amdgcn_mfma_f32_16x16x32_bf16(a0, b2, c, 0, 0, 0);      \
                c = __builtin_amdgcn_mfma_f32_16x16x32_bf16(a1, b0, c, 0, 0, 0);      \
                c = __builtin_amdgcn_mfma_f32_16x16x32_bf16(a0, b1, c, 0, 0, 0);      \
                c = __builtin_amdgcn_mfma_f32_16x16x32_bf16(a0, b0, c, 0, 0, 0);      \
                acc[nt * 4 + G] = c;                                                  \
            }                                                                         \
        }                                                                             \
    } while (0)

    LOADX(xP, 0);
    for (int it = 0; it < NSLICE / 2; ++it) {
        const int s = 2 * it;
        LOADB(bP, s);            // B needed in ~500 cyc: covered by split VALU + TLP
        LOADX(xQ, s + 1);        // x needed next slice: full lead
        COMPUTE(xP, bP);
        LOADB(bQ, s + 1);
        const int s2 = (s + 2) & (NSLICE - 1);   // last iter wraps to 0, never used
        LOADX(xP, s2);
        COMPUTE(xQ, bQ);
    }
#undef LOADX
#undef LOADB
#undef COMPUTE

    // C/D layout (proven rounds 4-6): col = lane&15 (expert), row = g*4+q (token)
#pragma unroll
    for (int nt = 0; nt < 4; ++nt)
#pragma unroll
        for (int G = 0; G < 4; ++G)
#pragma unroll
            for (int q = 0; q < 4; ++q)
                part_lds[wv][G * 16 + g * 4 + q][nt * 16 + r] = acc[nt * 4 + G][q];

    __syncthreads();

    // ---- epilogue: 8 tokens per wave; lane == expert (bit-identical to round 6) ----
    const float bias_l = bias[lane];
#pragma unroll 1
    for (int i = 0; i < 8; ++i) {
        const int tok = wv * 8 + i;
        float logit = 0.f;
#pragma unroll
        for (int kh = 0; kh < SPLITK; ++kh)     // fixed ascending order
            logit += part_lds[kh][tok][lane];
        const float s = 1.f / (1.f + expf(-logit));
        float myv  = s + bias_l;
        float outv = 0.f;
        int   outi = 0;
        float sum  = 0.f;
#pragma unroll
        for (int k = 0; k < TOPK; ++k) {
            float cv = myv;
            int   ci = lane;
#pragma unroll
            for (int off = 32; off; off >>= 1) {
                float ov = __shfl_xor(cv, off, 64);
                int   oi = __shfl_xor(ci, off, 64);
                if (ov > cv || (ov == cv && oi < ci)) { cv = ov; ci = oi; }
            }
            float ts = __shfl(s, ci, 64);      // unbiased score of winner
            sum += ts;
            if (lane == k)  { outv = ts; outi = ci; }
            if (lane == ci) { myv = -1e30f; }
        }
        const float denom = sum + 1e-20f;
        const size_t gt = (size_t)tok0 + tok;
        if (lane < TOPK) {
            out[gt * TOPK + lane] = (outv / denom) * ROUTE_SCALE;
            out[(size_t)NTOK * TOPK + gt * TOPK + lane] = (float)outi;
            atomicAdd(&hist[outi], 1);
        }
    }

    __syncthreads();
    if (t < NE) {
        int c = hist[t];
        if (c) atomicAdd(&out[(size_t)NTOK * TOPK * 2 + t], (float)c);
    }
}

extern "C" void kernel_launch(void* const* d_in, const int* in_sizes, int n_in,
                              void* d_out, int out_size, void* d_ws, size_t ws_size,
                              hipStream_t stream)
{
    const float* x    = (const float*)d_in[0];
    const float* gw   = (const float*)d_in[1];
    const float* bias = (const float*)d_in[2];
    float* out = (float*)d_out;
    uint4* wS  = (uint4*)d_ws;   // 1.5 MB

    // histogram region must start at zero every call
    hipMemsetAsync(out + (size_t)NTOK * TOPK * 2, 0, NE * sizeof(float), stream);

    prep_w<<<128, 256, 0, stream>>>(gw, wS);
    router_fused<<<NTOK / 64, 512, 0, stream>>>(x, wS, bias, out);
}